// Round 1
// baseline (224.133 us; speedup 1.0000x reference)
//
#include <hip/hip_runtime.h>
#include <hip/hip_bf16.h>
#include <stdint.h>

#define HIDDEN 1024
#define SEQL   2048
#define NB     2
#define NH     16
#define DH     64
#define MTOT   (NB * SEQL)   // 4096

typedef __bf16 bf16x8 __attribute__((ext_vector_type(8)));
typedef __bf16 bf16x4 __attribute__((ext_vector_type(4)));
typedef float  f32x4  __attribute__((ext_vector_type(4)));

// ---------------------------------------------------------------- convert
__global__ void cvt_f32_bf16(const float* __restrict__ src,
                             __bf16* __restrict__ dst, int n4) {
    int i = blockIdx.x * blockDim.x + threadIdx.x;
    if (i < n4) {
        float4 v = reinterpret_cast<const float4*>(src)[i];
        bf16x4 o = { (__bf16)v.x, (__bf16)v.y, (__bf16)v.z, (__bf16)v.w };
        reinterpret_cast<bf16x4*>(dst)[i] = o;
    }
}

// ---------------------------------------------------------------- V transpose
// V [MTOT][HIDDEN] (row = b*SEQL+s, col = h*DH+d)  ->  Vt [B*H][DH][SEQL]
__global__ void transpose_v_kernel(const __bf16* __restrict__ V,
                                   __bf16* __restrict__ Vt) {
    int idx = blockIdx.x * 256 + threadIdx.x;          // 0 .. 4M-1
    int s  = idx & (SEQL - 1);
    int d  = (idx >> 11) & (DH - 1);
    int bh = idx >> 17;
    int b  = bh >> 4, h = bh & 15;
    Vt[idx] = V[((size_t)(b * SEQL + s)) * HIDDEN + h * DH + d];
}

// ---------------------------------------------------------------- GEMM  C = A @ B^T + bias
// A [M][K] bf16, Bw [N][K] bf16, C [M][N] (bf16 or f32). M,N % 128 == 0, K % 32 == 0.
template <int OUTF32>
__global__ __launch_bounds__(256) void gemm_bt(const __bf16* __restrict__ A,
                                               const __bf16* __restrict__ Bw,
                                               const float* __restrict__ bias,
                                               void* __restrict__ Cout,
                                               int M, int N, int K) {
    __shared__ __bf16 As[128 * 32];
    __shared__ __bf16 Bs[128 * 32];

    const int tid = threadIdx.x;
    const int w = tid >> 6, l = tid & 63, g = l >> 4, lc = l & 15;
    const int wr = (w >> 1) * 64, wc = (w & 1) * 64;
    const int bm = blockIdx.x * 128, bn = blockIdx.y * 128;
    const int row = tid >> 2, ch = tid & 3;

    const __bf16* Arow0 = A  + (size_t)(bm + row) * K + ch * 8;
    const __bf16* Arow1 = Arow0 + (size_t)64 * K;
    const __bf16* Brow0 = Bw + (size_t)(bn + row) * K + ch * 8;
    const __bf16* Brow1 = Brow0 + (size_t)64 * K;

    f32x4 acc[4][4];
    const f32x4 z4 = {0.f, 0.f, 0.f, 0.f};
#pragma unroll
    for (int i = 0; i < 4; ++i)
#pragma unroll
        for (int j = 0; j < 4; ++j) acc[i][j] = z4;

    int4 ra0 = *(const int4*)(Arow0);
    int4 ra1 = *(const int4*)(Arow1);
    int4 rb0 = *(const int4*)(Brow0);
    int4 rb1 = *(const int4*)(Brow1);

    for (int kt = 0; kt < K; kt += 32) {
        *(int4*)&As[row * 32 + ch * 8]        = ra0;
        *(int4*)&As[(64 + row) * 32 + ch * 8] = ra1;
        *(int4*)&Bs[row * 32 + ch * 8]        = rb0;
        *(int4*)&Bs[(64 + row) * 32 + ch * 8] = rb1;
        __syncthreads();

        if (kt + 32 < K) {                    // prefetch next tile (latency hidden by MFMA)
            ra0 = *(const int4*)(Arow0 + kt + 32);
            ra1 = *(const int4*)(Arow1 + kt + 32);
            rb0 = *(const int4*)(Brow0 + kt + 32);
            rb1 = *(const int4*)(Brow1 + kt + 32);
        }

        bf16x8 af[4], bfr[4];
#pragma unroll
        for (int i = 0; i < 4; ++i)
            af[i] = *(const bf16x8*)&As[(wr + i * 16 + lc) * 32 + g * 8];
#pragma unroll
        for (int j = 0; j < 4; ++j)
            bfr[j] = *(const bf16x8*)&Bs[(wc + j * 16 + lc) * 32 + g * 8];
#pragma unroll
        for (int i = 0; i < 4; ++i)
#pragma unroll
            for (int j = 0; j < 4; ++j)
                acc[i][j] = __builtin_amdgcn_mfma_f32_16x16x32_bf16(af[i], bfr[j], acc[i][j], 0, 0, 0);
        __syncthreads();
    }

#pragma unroll
    for (int i = 0; i < 4; ++i) {
        int r0 = bm + wr + i * 16 + g * 4;
#pragma unroll
        for (int j = 0; j < 4; ++j) {
            int c = bn + wc + j * 16 + lc;
            float bb = bias[c];
#pragma unroll
            for (int r = 0; r < 4; ++r) {
                float v = acc[i][j][r] + bb;
                if constexpr (OUTF32)
                    ((float*)Cout)[(size_t)(r0 + r) * N + c] = v;
                else
                    ((__bf16*)Cout)[(size_t)(r0 + r) * N + c] = (__bf16)v;
            }
        }
    }
}

// ---------------------------------------------------------------- flash attention
// Q,K [MTOT][HIDDEN] bf16; Vt [B*H][DH][SEQL] bf16; Ctx [MTOT][HIDDEN] bf16.
// grid = (SEQL/64, NB*NH), block = 256 (4 waves; wave w owns 16 q-rows).
__global__ __launch_bounds__(256) void attn_kernel(const __bf16* __restrict__ Q,
                                                   const __bf16* __restrict__ K,
                                                   const __bf16* __restrict__ Vt,
                                                   __bf16* __restrict__ Ctx) {
    __shared__ __bf16 q_lds[64][72];
    __shared__ __bf16 k_lds[64][72];
    __shared__ __bf16 vt_lds[64][72];
    __shared__ __bf16 p_lds[4][16][72];

    const int tid = threadIdx.x;
    const int w = tid >> 6, l = tid & 63, g = l >> 4, lc = l & 15;
    const int qt = blockIdx.x, bh = blockIdx.y;
    const int b = bh >> 4, h = bh & 15;
    const int qbase = qt * 64;

    const __bf16* Qg  = Q + (size_t)b * SEQL * HIDDEN + h * DH;
    const __bf16* Kg  = K + (size_t)b * SEQL * HIDDEN + h * DH;
    const __bf16* Vtg = Vt + (size_t)bh * DH * SEQL;

    const int srow = tid >> 3, sch = tid & 7;   // staging: 32 rows x 8 chunks of 16B

    {   // stage Q tile once
        int4 q0 = *(const int4*)(Qg + (size_t)(qbase + srow) * HIDDEN + sch * 8);
        int4 q1 = *(const int4*)(Qg + (size_t)(qbase + 32 + srow) * HIDDEN + sch * 8);
        *(int4*)&q_lds[srow][sch * 8]      = q0;
        *(int4*)&q_lds[32 + srow][sch * 8] = q1;
    }

    int4 rk0, rk1, rv0, rv1;
    auto preload = [&](int kbase) {
        rk0 = *(const int4*)(Kg + (size_t)(kbase + srow) * HIDDEN + sch * 8);
        rk1 = *(const int4*)(Kg + (size_t)(kbase + 32 + srow) * HIDDEN + sch * 8);
        rv0 = *(const int4*)(Vtg + (size_t)srow * SEQL + kbase + sch * 8);
        rv1 = *(const int4*)(Vtg + (size_t)(32 + srow) * SEQL + kbase + sch * 8);
    };
    preload(0);

    float m_r[4], l_r[4];
    f32x4 o[4];
    const f32x4 z4 = {0.f, 0.f, 0.f, 0.f};
#pragma unroll
    for (int r = 0; r < 4; ++r) { m_r[r] = -1e30f; l_r[r] = 0.f; }
#pragma unroll
    for (int jd = 0; jd < 4; ++jd) o[jd] = z4;

    bf16x8 qf0, qf1;

    for (int kt = 0; kt < SEQL / 64; ++kt) {
        const int kbase = kt * 64;
        *(int4*)&k_lds[srow][sch * 8]       = rk0;
        *(int4*)&k_lds[32 + srow][sch * 8]  = rk1;
        *(int4*)&vt_lds[srow][sch * 8]      = rv0;
        *(int4*)&vt_lds[32 + srow][sch * 8] = rv1;
        __syncthreads();   // staging visible

        if (kt == 0) {
            qf0 = *(const bf16x8*)&q_lds[w * 16 + lc][g * 8];
            qf1 = *(const bf16x8*)&q_lds[w * 16 + lc][32 + g * 8];
        }
        if (kt + 1 < SEQL / 64) preload(kbase + 64);

        // S = Q K^T  (wave's 16 q-rows x 64 k-cols)
        f32x4 s[4];
#pragma unroll
        for (int jn = 0; jn < 4; ++jn) {
            bf16x8 kb0 = *(const bf16x8*)&k_lds[jn * 16 + lc][g * 8];
            bf16x8 kb1 = *(const bf16x8*)&k_lds[jn * 16 + lc][32 + g * 8];
            f32x4 a = z4;
            a = __builtin_amdgcn_mfma_f32_16x16x32_bf16(qf0, kb0, a, 0, 0, 0);
            a = __builtin_amdgcn_mfma_f32_16x16x32_bf16(qf1, kb1, a, 0, 0, 0);
            s[jn] = a;
        }

        // scale + diagonal mask
        const int qrow0 = qbase + w * 16 + g * 4;
#pragma unroll
        for (int jn = 0; jn < 4; ++jn) {
            const int kkc = kbase + jn * 16 + lc;
#pragma unroll
            for (int r = 0; r < 4; ++r) {
                float sv = s[jn][r] * 0.125f;
                if (kkc == qrow0 + r) sv = -1e30f;
                s[jn][r] = sv;
            }
        }

        // wave-parallel row max (reduce across 16 lanes of the group)
        float pm[4];
#pragma unroll
        for (int r = 0; r < 4; ++r)
            pm[r] = fmaxf(fmaxf(s[0][r], s[1][r]), fmaxf(s[2][r], s[3][r]));
#pragma unroll
        for (int off = 1; off < 16; off <<= 1)
#pragma unroll
            for (int r = 0; r < 4; ++r)
                pm[r] = fmaxf(pm[r], __shfl_xor(pm[r], off, 64));

        float al[4];
#pragma unroll
        for (int r = 0; r < 4; ++r) {
            float mn = fmaxf(m_r[r], pm[r]);
            al[r] = __expf(m_r[r] - mn);
            m_r[r] = mn;
        }

        float rs[4] = {0.f, 0.f, 0.f, 0.f};
#pragma unroll
        for (int jn = 0; jn < 4; ++jn)
#pragma unroll
            for (int r = 0; r < 4; ++r) {
                float p = __expf(s[jn][r] - m_r[r]);
                s[jn][r] = p;
                rs[r] += p;
            }
#pragma unroll
        for (int off = 1; off < 16; off <<= 1)
#pragma unroll
            for (int r = 0; r < 4; ++r)
                rs[r] += __shfl_xor(rs[r], off, 64);
#pragma unroll
        for (int r = 0; r < 4; ++r) l_r[r] = l_r[r] * al[r] + rs[r];
#pragma unroll
        for (int jd = 0; jd < 4; ++jd)
#pragma unroll
            for (int r = 0; r < 4; ++r) o[jd][r] *= al[r];

        // P -> per-wave LDS (C-layout -> A-layout round trip)
#pragma unroll
        for (int jn = 0; jn < 4; ++jn)
#pragma unroll
            for (int r = 0; r < 4; ++r)
                p_lds[w][g * 4 + r][jn * 16 + lc] = (__bf16)s[jn][r];
        asm volatile("s_waitcnt lgkmcnt(0)" ::: "memory");

        bf16x8 pa0 = *(const bf16x8*)&p_lds[w][lc][g * 8];
        bf16x8 pa1 = *(const bf16x8*)&p_lds[w][lc][32 + g * 8];
#pragma unroll
        for (int jd = 0; jd < 4; ++jd) {
            bf16x8 v0 = *(const bf16x8*)&vt_lds[jd * 16 + lc][g * 8];
            bf16x8 v1 = *(const bf16x8*)&vt_lds[jd * 16 + lc][32 + g * 8];
            o[jd] = __builtin_amdgcn_mfma_f32_16x16x32_bf16(pa0, v0, o[jd], 0, 0, 0);
            o[jd] = __builtin_amdgcn_mfma_f32_16x16x32_bf16(pa1, v1, o[jd], 0, 0, 0);
        }
        __syncthreads();   // all waves done reading k/vt before next stage
    }

    float inv[4];
#pragma unroll
    for (int r = 0; r < 4; ++r) inv[r] = 1.0f / l_r[r];
    const int qrow0 = qbase + w * 16 + g * 4;
#pragma unroll
    for (int jd = 0; jd < 4; ++jd) {
        int c = h * DH + jd * 16 + lc;
#pragma unroll
        for (int r = 0; r < 4; ++r) {
            float v = o[jd][r] * inv[r];
            Ctx[(size_t)(b * SEQL + qrow0 + r) * HIDDEN + c] = (__bf16)v;
        }
    }
}

// ---------------------------------------------------------------- launch
extern "C" void kernel_launch(void* const* d_in, const int* in_sizes, int n_in,
                              void* d_out, int out_size, void* d_ws, size_t ws_size,
                              hipStream_t stream) {
    const float* H  = (const float*)d_in[0];
    const float* Wq = (const float*)d_in[1];
    const float* bq = (const float*)d_in[2];
    const float* Wk = (const float*)d_in[3];
    const float* bk = (const float*)d_in[4];
    const float* Wv = (const float*)d_in[5];
    const float* bv = (const float*)d_in[6];
    const float* Wd = (const float*)d_in[7];
    const float* bd = (const float*)d_in[8];
    float* out = (float*)d_out;

    char* ws = (char*)d_ws;
    const size_t MB = 1024 * 1024;
    __bf16* Hb  = (__bf16*)(ws + 0 * MB);    // 8 MB
    __bf16* Wqb = (__bf16*)(ws + 8 * MB);    // 2 MB
    __bf16* Wkb = (__bf16*)(ws + 10 * MB);
    __bf16* Wvb = (__bf16*)(ws + 12 * MB);
    __bf16* Wdb = (__bf16*)(ws + 14 * MB);
    __bf16* Qb  = (__bf16*)(ws + 16 * MB);   // 8 MB each
    __bf16* Kb  = (__bf16*)(ws + 24 * MB);
    __bf16* Vb  = (__bf16*)(ws + 32 * MB);
    __bf16* Vtb = (__bf16*)(ws + 40 * MB);
    __bf16* Ctx = (__bf16*)(ws + 48 * MB);   // total 56 MB
    if (ws_size < 56 * MB) return;

    cvt_f32_bf16<<<(MTOT * HIDDEN / 4 + 255) / 256, 256, 0, stream>>>(H, Hb, MTOT * HIDDEN / 4);
    cvt_f32_bf16<<<(HIDDEN * HIDDEN / 4 + 255) / 256, 256, 0, stream>>>(Wq, Wqb, HIDDEN * HIDDEN / 4);
    cvt_f32_bf16<<<(HIDDEN * HIDDEN / 4 + 255) / 256, 256, 0, stream>>>(Wk, Wkb, HIDDEN * HIDDEN / 4);
    cvt_f32_bf16<<<(HIDDEN * HIDDEN / 4 + 255) / 256, 256, 0, stream>>>(Wv, Wvb, HIDDEN * HIDDEN / 4);
    cvt_f32_bf16<<<(HIDDEN * HIDDEN / 4 + 255) / 256, 256, 0, stream>>>(Wd, Wdb, HIDDEN * HIDDEN / 4);

    dim3 ggrid(MTOT / 128, HIDDEN / 128);
    gemm_bt<0><<<ggrid, 256, 0, stream>>>(Hb, Wqb, bq, Qb, MTOT, HIDDEN, HIDDEN);
    gemm_bt<0><<<ggrid, 256, 0, stream>>>(Hb, Wkb, bk, Kb, MTOT, HIDDEN, HIDDEN);
    gemm_bt<0><<<ggrid, 256, 0, stream>>>(Hb, Wvb, bv, Vb, MTOT, HIDDEN, HIDDEN);

    transpose_v_kernel<<<(MTOT * HIDDEN) / 256, 256, 0, stream>>>(Vb, Vtb);

    attn_kernel<<<dim3(SEQL / 64, NB * NH), 256, 0, stream>>>(Qb, Kb, Vtb, Ctx);

    gemm_bt<1><<<ggrid, 256, 0, stream>>>(Ctx, Wdb, bd, out, MTOT, HIDDEN, HIDDEN);
}

// Round 2
// 170.441 us; speedup vs baseline: 1.3150x; 1.3150x over previous
//
#include <hip/hip_runtime.h>
#include <hip/hip_bf16.h>
#include <stdint.h>

#define HIDDEN 1024
#define SEQL   2048
#define NB     2
#define NH     16
#define DH     64
#define MTOT   (NB * SEQL)   // 4096

typedef __bf16 bf16x8 __attribute__((ext_vector_type(8)));
typedef __bf16 bf16x4 __attribute__((ext_vector_type(4)));
typedef float  f32x4  __attribute__((ext_vector_type(4)));
typedef float  f32x16 __attribute__((ext_vector_type(16)));

// ---------------------------------------------------------------- convert
__global__ void cvt_f32_bf16(const float* __restrict__ src,
                             __bf16* __restrict__ dst, int n4) {
    int i = blockIdx.x * blockDim.x + threadIdx.x;
    if (i < n4) {
        float4 v = reinterpret_cast<const float4*>(src)[i];
        bf16x4 o = { (__bf16)v.x, (__bf16)v.y, (__bf16)v.z, (__bf16)v.w };
        reinterpret_cast<bf16x4*>(dst)[i] = o;
    }
}

// ---------------------------------------------------------------- V transpose
// V [MTOT][HIDDEN] -> Vt [B*H][DH][SEQL]
__global__ void transpose_v_kernel(const __bf16* __restrict__ V,
                                   __bf16* __restrict__ Vt) {
    int idx = blockIdx.x * 256 + threadIdx.x;
    int s  = idx & (SEQL - 1);
    int d  = (idx >> 11) & (DH - 1);
    int bh = idx >> 17;
    int b  = bh >> 4, h = bh & 15;
    Vt[idx] = V[((size_t)(b * SEQL + s)) * HIDDEN + h * DH + d];
}

// ---------------------------------------------------------------- GEMM  C = (A @ B^T + bias) * oscale
template <int OUTF32>
__global__ __launch_bounds__(256) void gemm_bt(const __bf16* __restrict__ A,
                                               const __bf16* __restrict__ Bw,
                                               const float* __restrict__ bias,
                                               void* __restrict__ Cout,
                                               int M, int N, int K, float oscale) {
    __shared__ __bf16 As[128 * 32];
    __shared__ __bf16 Bs[128 * 32];

    const int tid = threadIdx.x;
    const int w = tid >> 6, l = tid & 63, g = l >> 4, lc = l & 15;
    const int wr = (w >> 1) * 64, wc = (w & 1) * 64;
    const int bm = blockIdx.x * 128, bn = blockIdx.y * 128;
    const int row = tid >> 2, ch = tid & 3;

    const __bf16* Arow0 = A  + (size_t)(bm + row) * K + ch * 8;
    const __bf16* Arow1 = Arow0 + (size_t)64 * K;
    const __bf16* Brow0 = Bw + (size_t)(bn + row) * K + ch * 8;
    const __bf16* Brow1 = Brow0 + (size_t)64 * K;

    f32x4 acc[4][4];
    const f32x4 z4 = {0.f, 0.f, 0.f, 0.f};
#pragma unroll
    for (int i = 0; i < 4; ++i)
#pragma unroll
        for (int j = 0; j < 4; ++j) acc[i][j] = z4;

    int4 ra0 = *(const int4*)(Arow0);
    int4 ra1 = *(const int4*)(Arow1);
    int4 rb0 = *(const int4*)(Brow0);
    int4 rb1 = *(const int4*)(Brow1);

    for (int kt = 0; kt < K; kt += 32) {
        *(int4*)&As[row * 32 + ch * 8]        = ra0;
        *(int4*)&As[(64 + row) * 32 + ch * 8] = ra1;
        *(int4*)&Bs[row * 32 + ch * 8]        = rb0;
        *(int4*)&Bs[(64 + row) * 32 + ch * 8] = rb1;
        __syncthreads();

        if (kt + 32 < K) {
            ra0 = *(const int4*)(Arow0 + kt + 32);
            ra1 = *(const int4*)(Arow1 + kt + 32);
            rb0 = *(const int4*)(Brow0 + kt + 32);
            rb1 = *(const int4*)(Brow1 + kt + 32);
        }

        bf16x8 af[4], bfr[4];
#pragma unroll
        for (int i = 0; i < 4; ++i)
            af[i] = *(const bf16x8*)&As[(wr + i * 16 + lc) * 32 + g * 8];
#pragma unroll
        for (int j = 0; j < 4; ++j)
            bfr[j] = *(const bf16x8*)&Bs[(wc + j * 16 + lc) * 32 + g * 8];
#pragma unroll
        for (int i = 0; i < 4; ++i)
#pragma unroll
            for (int j = 0; j < 4; ++j)
                acc[i][j] = __builtin_amdgcn_mfma_f32_16x16x32_bf16(af[i], bfr[j], acc[i][j], 0, 0, 0);
        __syncthreads();
    }

#pragma unroll
    for (int i = 0; i < 4; ++i) {
        int r0 = bm + wr + i * 16 + g * 4;
#pragma unroll
        for (int j = 0; j < 4; ++j) {
            int c = bn + wc + j * 16 + lc;
            float bb = bias[c];
#pragma unroll
            for (int r = 0; r < 4; ++r) {
                float v = (acc[i][j][r] + bb) * oscale;
                if constexpr (OUTF32)
                    ((float*)Cout)[(size_t)(r0 + r) * N + c] = v;
                else
                    ((__bf16*)Cout)[(size_t)(r0 + r) * N + c] = (__bf16)v;
            }
        }
    }
}

// ---------------------------------------------------------------- attention helpers
__device__ __forceinline__ unsigned cvtpk(float lo, float hi) {
    unsigned r;
    asm("v_cvt_pk_bf16_f32 %0, %1, %2" : "=v"(r) : "v"(lo), "v"(hi));
    return r;
}
__device__ __forceinline__ void pswap(unsigned& a, unsigned& b) {
    asm volatile("v_permlane32_swap_b32 %0, %1" : "+v"(a), "+v"(b));
}

// ---------------------------------------------------------------- flash attention (swapped-QK, 32x32 MFMA)
// Q,K [MTOT][HIDDEN] bf16 (Q pre-scaled by 1/8); Vt [B*H][DH][SEQL]; Ctx [MTOT][HIDDEN] bf16.
// grid = (SEQL/128, NB*NH), block = 256 (4 waves, 32 q-rows each).
__global__ __launch_bounds__(256) void attn_kernel(const __bf16* __restrict__ Q,
                                                   const __bf16* __restrict__ K,
                                                   const __bf16* __restrict__ Vt,
                                                   __bf16* __restrict__ Ctx) {
    __shared__ __bf16 k_lds[2][64][64];   // XOR-swizzled: col ^= (row&7)<<3
    __shared__ __bf16 v_lds[2][64][64];   // Vt tile, rows = d, cols = k-local
    __shared__ float  bc[4][32];          // per-wave broadcast (al / 1/l)

    const int tid = threadIdx.x;
    const int w  = tid >> 6;
    const int l  = tid & 63;
    const int ql = l & 31;     // this lane's q (QK^T C-col) and d-local (PV C-col)
    const int lh = l >> 5;     // lane half

    const int bh = blockIdx.y;
    const int b = bh >> 4, hd = bh & 15;
    const int qw = blockIdx.x * 128 + w * 32;   // wave's q window start

    const __bf16* Qg = Q  + (size_t)b * SEQL * HIDDEN + hd * DH;
    const __bf16* Kg = K  + (size_t)b * SEQL * HIDDEN + hd * DH;
    const __bf16* Vg = Vt + (size_t)bh * DH * SEQL;

    // Q fragments (B-operand): lane holds q-row qw+ql, d-slice c*16 + lh*8
    bf16x8 qf[4];
    {
        const __bf16* qp = Qg + (size_t)(qw + ql) * HIDDEN + lh * 8;
#pragma unroll
        for (int c = 0; c < 4; ++c) qf[c] = *(const bf16x8*)(qp + c * 16);
    }

    const int srow = tid >> 3, sch = tid & 7;
    const int scol = (sch * 8) ^ ((srow & 7) << 3);

    {   // prologue: stage tile 0 into buf 0
        const __bf16* kp = Kg + (size_t)srow * HIDDEN + sch * 8;
        const __bf16* vp = Vg + (size_t)srow * SEQL + sch * 8;
        int4 a0 = *(const int4*)kp;
        int4 a1 = *(const int4*)(kp + (size_t)32 * HIDDEN);
        int4 b0 = *(const int4*)vp;
        int4 b1 = *(const int4*)(vp + (size_t)32 * SEQL);
        *(int4*)&k_lds[0][srow][scol]      = a0;
        *(int4*)&k_lds[0][srow + 32][scol] = a1;
        *(int4*)&v_lds[0][srow][scol]      = b0;
        *(int4*)&v_lds[0][srow + 32][scol] = b1;
    }
    __syncthreads();

    f32x16 o0, o1;
#pragma unroll
    for (int r = 0; r < 16; ++r) { o0[r] = 0.f; o1[r] = 0.f; }
    float m_r = -1e30f, l_r = 0.f;

    const int NT = SEQL / 64;
    const int rsw = (ql & 7) << 3;

    for (int kt = 0; kt < NT; ++kt) {
        const int buf = kt & 1;
        const int kb = kt * 64;

        // early-issue next tile's global loads (latency hides under QK+softmax+PV)
        int4 nk0, nk1, nv0, nv1;
        const bool hn = (kt + 1 < NT);
        if (hn) {
            const __bf16* kp = Kg + (size_t)(kb + 64 + srow) * HIDDEN + sch * 8;
            const __bf16* vp = Vg + (size_t)srow * SEQL + (kb + 64) + sch * 8;
            nk0 = *(const int4*)kp;
            nk1 = *(const int4*)(kp + (size_t)32 * HIDDEN);
            nv0 = *(const int4*)vp;
            nv1 = *(const int4*)(vp + (size_t)32 * SEQL);
        }

        // ---- QK^T (swapped: A=K, B=Q) -> lane owns q=qw+ql, 32 k-slots over regs
        f32x16 sA, sB;
#pragma unroll
        for (int r = 0; r < 16; ++r) { sA[r] = 0.f; sB[r] = 0.f; }
#pragma unroll
        for (int c = 0; c < 4; ++c) {
            bf16x8 k0 = *(const bf16x8*)&k_lds[buf][ql]     [(c * 16 + lh * 8) ^ rsw];
            bf16x8 k1 = *(const bf16x8*)&k_lds[buf][32 + ql][(c * 16 + lh * 8) ^ rsw];
            sA = __builtin_amdgcn_mfma_f32_32x32x16_bf16(k0, qf[c], sA, 0, 0, 0);
            sB = __builtin_amdgcn_mfma_f32_32x32x16_bf16(k1, qf[c], sB, 0, 0, 0);
        }

        float p[32];
#pragma unroll
        for (int r = 0; r < 16; ++r) { p[r] = sA[r]; p[16 + r] = sB[r]; }

        // diagonal mask, only when tile intersects wave's q-window (wave-uniform)
        if (kb < qw + 32 && qw < kb + 64) {
            const int qg = qw + ql;
#pragma unroll
            for (int i = 0; i < 32; ++i) {
                int kg = kb + ((i >> 4) << 5) + (i & 3) + ((i >> 2) & 3) * 8 + lh * 4;
                if (kg == qg) p[i] = -1e30f;
            }
        }

        // row max: lane-local over 32 regs + one cross-half combine
        float pm = p[0];
#pragma unroll
        for (int i = 1; i < 32; ++i) pm = fmaxf(pm, p[i]);
        pm = fmaxf(pm, __shfl_xor(pm, 32, 64));

        // defer-max rescale (T13, THR=8 in ln-domain)
        if (__any(pm > m_r + 8.f)) {
            float mn = fmaxf(m_r, pm);
            float al = __expf(m_r - mn);
            m_r = mn;
            l_r *= al;
            if (lh == 0) bc[w][ql] = al;
            asm volatile("s_waitcnt lgkmcnt(0)" ::: "memory");
            float ag[16];
#pragma unroll
            for (int r = 0; r < 16; ++r)
                ag[r] = bc[w][(r & 3) + (r >> 2) * 8 + lh * 4];
#pragma unroll
            for (int r = 0; r < 16; ++r) { o0[r] *= ag[r]; o1[r] *= ag[r]; }
        }

        // exp + row-sum
        float rs = 0.f;
#pragma unroll
        for (int i = 0; i < 32; ++i) { p[i] = __expf(p[i] - m_r); rs += p[i]; }
        rs += __shfl_xor(rs, 32, 64);
        l_r += rs;

        // P -> bf16 PV A-fragments fully in-register (T12)
        bf16x8 pa[4];   // [sub*2 + kslice]
#pragma unroll
        for (int s = 0; s < 2; ++s) {
            unsigned w0 = cvtpk(p[s * 16 + 0],  p[s * 16 + 1]);
            unsigned w1 = cvtpk(p[s * 16 + 2],  p[s * 16 + 3]);
            unsigned w2 = cvtpk(p[s * 16 + 4],  p[s * 16 + 5]);
            unsigned w3 = cvtpk(p[s * 16 + 6],  p[s * 16 + 7]);
            unsigned w4 = cvtpk(p[s * 16 + 8],  p[s * 16 + 9]);
            unsigned w5 = cvtpk(p[s * 16 + 10], p[s * 16 + 11]);
            unsigned w6 = cvtpk(p[s * 16 + 12], p[s * 16 + 13]);
            unsigned w7 = cvtpk(p[s * 16 + 14], p[s * 16 + 15]);
            pswap(w0, w2); pswap(w1, w3);
            pswap(w4, w6); pswap(w5, w7);
            uint4 lo4 = {w0, w1, w2, w3};
            uint4 hi4 = {w4, w5, w6, w7};
            pa[s * 2 + 0] = *(bf16x8*)&lo4;
            pa[s * 2 + 1] = *(bf16x8*)&hi4;
        }

        // ---- PV (A=P, B=V^T) -> lane owns d=ql (+32), q over regs
#pragma unroll
        for (int s = 0; s < 2; ++s)
#pragma unroll
            for (int sl = 0; sl < 2; ++sl) {
                const int col = s * 32 + sl * 16 + lh * 8;
                bf16x8 v0 = *(const bf16x8*)&v_lds[buf][ql]     [col ^ rsw];
                bf16x8 v1 = *(const bf16x8*)&v_lds[buf][32 + ql][col ^ rsw];
                o0 = __builtin_amdgcn_mfma_f32_32x32x16_bf16(pa[s * 2 + sl], v0, o0, 0, 0, 0);
                o1 = __builtin_amdgcn_mfma_f32_32x32x16_bf16(pa[s * 2 + sl], v1, o1, 0, 0, 0);
            }

        // write-late staging (T14)
        if (hn) {
            const int nb2 = buf ^ 1;
            *(int4*)&k_lds[nb2][srow][scol]      = nk0;
            *(int4*)&k_lds[nb2][srow + 32][scol] = nk1;
            *(int4*)&v_lds[nb2][srow][scol]      = nv0;
            *(int4*)&v_lds[nb2][srow + 32][scol] = nv1;
        }
        __syncthreads();
    }

    // epilogue: gather 1/l per q (cross-lane via per-wave LDS broadcast), write Ctx
    if (lh == 0) bc[w][ql] = 1.f / l_r;
    asm volatile("s_waitcnt lgkmcnt(0)" ::: "memory");
#pragma unroll
    for (int r = 0; r < 16; ++r) {
        int cr = (r & 3) + (r >> 2) * 8 + lh * 4;
        float iv = bc[w][cr];
        int qrow = qw + cr;
        __bf16* cp = Ctx + (size_t)(b * SEQL + qrow) * HIDDEN + hd * DH + ql;
        cp[0]  = (__bf16)(o0[r] * iv);
        cp[32] = (__bf16)(o1[r] * iv);
    }
}

// ---------------------------------------------------------------- launch
extern "C" void kernel_launch(void* const* d_in, const int* in_sizes, int n_in,
                              void* d_out, int out_size, void* d_ws, size_t ws_size,
                              hipStream_t stream) {
    const float* H  = (const float*)d_in[0];
    const float* Wq = (const float*)d_in[1];
    const float* bq = (const float*)d_in[2];
    const float* Wk = (const float*)d_in[3];
    const float* bk = (const float*)d_in[4];
    const float* Wv = (const float*)d_in[5];
    const float* bv = (const float*)d_in[6];
    const float* Wd = (const float*)d_in[7];
    const float* bd = (const float*)d_in[8];
    float* out = (float*)d_out;

    char* ws = (char*)d_ws;
    const size_t MB = 1024 * 1024;
    __bf16* Hb  = (__bf16*)(ws + 0 * MB);
    __bf16* Wqb = (__bf16*)(ws + 8 * MB);
    __bf16* Wkb = (__bf16*)(ws + 10 * MB);
    __bf16* Wvb = (__bf16*)(ws + 12 * MB);
    __bf16* Wdb = (__bf16*)(ws + 14 * MB);
    __bf16* Qb  = (__bf16*)(ws + 16 * MB);
    __bf16* Kb  = (__bf16*)(ws + 24 * MB);
    __bf16* Vb  = (__bf16*)(ws + 32 * MB);
    __bf16* Vtb = (__bf16*)(ws + 40 * MB);
    __bf16* Ctx = (__bf16*)(ws + 48 * MB);
    if (ws_size < 56 * MB) return;

    cvt_f32_bf16<<<(MTOT * HIDDEN / 4 + 255) / 256, 256, 0, stream>>>(H, Hb, MTOT * HIDDEN / 4);
    cvt_f32_bf16<<<(HIDDEN * HIDDEN / 4 + 255) / 256, 256, 0, stream>>>(Wq, Wqb, HIDDEN * HIDDEN / 4);
    cvt_f32_bf16<<<(HIDDEN * HIDDEN / 4 + 255) / 256, 256, 0, stream>>>(Wk, Wkb, HIDDEN * HIDDEN / 4);
    cvt_f32_bf16<<<(HIDDEN * HIDDEN / 4 + 255) / 256, 256, 0, stream>>>(Wv, Wvb, HIDDEN * HIDDEN / 4);
    cvt_f32_bf16<<<(HIDDEN * HIDDEN / 4 + 255) / 256, 256, 0, stream>>>(Wd, Wdb, HIDDEN * HIDDEN / 4);

    dim3 ggrid(MTOT / 128, HIDDEN / 128);
    // Q pre-scaled by 1/sqrt(DH) = 1/8 (folds attention scale into GEMM epilogue)
    gemm_bt<0><<<ggrid, 256, 0, stream>>>(Hb, Wqb, bq, Qb, MTOT, HIDDEN, HIDDEN, 0.125f);
    gemm_bt<0><<<ggrid, 256, 0, stream>>>(Hb, Wkb, bk, Kb, MTOT, HIDDEN, HIDDEN, 1.0f);
    gemm_bt<0><<<ggrid, 256, 0, stream>>>(Hb, Wvb, bv, Vb, MTOT, HIDDEN, HIDDEN, 1.0f);

    transpose_v_kernel<<<(MTOT * HIDDEN) / 256, 256, 0, stream>>>(Vb, Vtb);

    attn_kernel<<<dim3(SEQL / 128, NB * NH), 256, 0, stream>>>(Qb, Kb, Vtb, Ctx);

    gemm_bt<1><<<ggrid, 256, 0, stream>>>(Ctx, Wdb, bd, out, MTOT, HIDDEN, HIDDEN, 1.0f);
}

// Round 3
// 137.374 us; speedup vs baseline: 1.6315x; 1.2407x over previous
//
#include <hip/hip_runtime.h>
#include <hip/hip_bf16.h>
#include <stdint.h>

#define HIDDEN 1024
#define SEQL   2048
#define NB     2
#define NH     16
#define DH     64
#define MTOT   (NB * SEQL)   // 4096
#define QKVLD  3072          // fused QKV row stride
#define SCALE_Q 0.18033688011112042f   // 0.125 * log2(e)

typedef __bf16 bf16x8 __attribute__((ext_vector_type(8)));
typedef __bf16 bf16x4 __attribute__((ext_vector_type(4)));
typedef float  f32x4  __attribute__((ext_vector_type(4)));
typedef float  f32x16 __attribute__((ext_vector_type(16)));

__device__ __forceinline__ void gload16(const void* g, void* l) {
    __builtin_amdgcn_global_load_lds(
        (const __attribute__((address_space(1))) void*)g,
        (__attribute__((address_space(3))) void*)l, 16, 0, 0);
}
__device__ __forceinline__ float exp2fast(float x) {
    float r;
    asm("v_exp_f32 %0, %1" : "=v"(r) : "v"(x));
    return r;
}
__device__ __forceinline__ unsigned cvtpk(float lo, float hi) {
    unsigned r;
    asm("v_cvt_pk_bf16_f32 %0, %1, %2" : "=v"(r) : "v"(lo), "v"(hi));
    return r;
}
__device__ __forceinline__ void pswap(unsigned& a, unsigned& b) {
    asm volatile("v_permlane32_swap_b32 %0, %1" : "+v"(a), "+v"(b));
}

// ---------------------------------------------------------------- converts
__global__ void cvt_f32_bf16(const float* __restrict__ src,
                             __bf16* __restrict__ dst, int n4) {
    int i = blockIdx.x * blockDim.x + threadIdx.x;
    if (i < n4) {
        float4 v = reinterpret_cast<const float4*>(src)[i];
        bf16x4 o = { (__bf16)v.x, (__bf16)v.y, (__bf16)v.z, (__bf16)v.w };
        reinterpret_cast<bf16x4*>(dst)[i] = o;
    }
}

// 4 weight matrices -> one contiguous bf16 region [Wq*s | Wk | Wv | Wd]
__global__ void cvt_w4(const float* __restrict__ Wq, const float* __restrict__ Wk,
                       const float* __restrict__ Wv, const float* __restrict__ Wd,
                       __bf16* __restrict__ dst) {
    int seg = blockIdx.y;
    const float* src = seg == 0 ? Wq : seg == 1 ? Wk : seg == 2 ? Wv : Wd;
    float sc = (seg == 0) ? SCALE_Q : 1.0f;
    int i = blockIdx.x * 256 + threadIdx.x;          // 0 .. 262143
    float4 v = reinterpret_cast<const float4*>(src)[i];
    bf16x4 o = { (__bf16)(v.x * sc), (__bf16)(v.y * sc),
                 (__bf16)(v.z * sc), (__bf16)(v.w * sc) };
    reinterpret_cast<bf16x4*>(dst)[(size_t)seg * 262144 + i] = o;
}

__global__ void pack_bias(const float* __restrict__ bq, const float* __restrict__ bk,
                          const float* __restrict__ bv, float* __restrict__ dst) {
    int i = blockIdx.x * 256 + threadIdx.x;          // 0 .. 3071
    float v = (i < 1024) ? bq[i] * SCALE_Q : (i < 2048) ? bk[i - 1024] : bv[i - 2048];
    dst[i] = v;
}

// ---------------------------------------------------------------- V transpose (LDS-tiled)
// QKV V-segment (cols 2048..3071) -> Vt [B*H][DH][SEQL]
__global__ __launch_bounds__(256) void transpose_v(const __bf16* __restrict__ QKV,
                                                   __bf16* __restrict__ Vt) {
    __shared__ __bf16 t[64][66];
    const int st = blockIdx.x, bh = blockIdx.y;
    const int b = bh >> 4, h = bh & 15;
    const int tid = threadIdx.x;
    const int r = tid >> 3, c = tid & 7;
    const __bf16* src = QKV + (size_t)(b * SEQL + st * 64) * QKVLD + 2048 + h * 64;
    *(int4*)&t[r][c * 8]      = *(const int4*)(src + (size_t)r * QKVLD + c * 8);
    *(int4*)&t[r + 32][c * 8] = *(const int4*)(src + (size_t)(r + 32) * QKVLD + c * 8);
    __syncthreads();
    __bf16* dst = Vt + (size_t)bh * DH * SEQL + st * 64;
    const int d = tid >> 3;
    __bf16 tmp0[8], tmp1[8];
#pragma unroll
    for (int j = 0; j < 8; ++j) {
        tmp0[j] = t[c * 8 + j][d];
        tmp1[j] = t[c * 8 + j][d + 32];
    }
    *(int4*)(dst + (size_t)d * SEQL + c * 8)        = *(int4*)tmp0;
    *(int4*)(dst + (size_t)(d + 32) * SEQL + c * 8) = *(int4*)tmp1;
}

// ---------------------------------------------------------------- fused QKV GEMM (m97 structure)
// A [4096][1024] bf16, Bw [3072][1024] bf16, C [4096][3072] bf16. global_load_lds staging.
__global__ __launch_bounds__(256) void gemm_qkv(const __bf16* __restrict__ A,
                                                const __bf16* __restrict__ Bw,
                                                const float* __restrict__ bias,
                                                __bf16* __restrict__ C) {
    __shared__ __bf16 As[128 * 32];
    __shared__ __bf16 Bs[128 * 32];
    const int K = 1024, N = QKVLD;

    int bid = blockIdx.x;                       // 768 blocks
    int swz = (bid & 7) * 96 + (bid >> 3);      // XCD-chunked (768 % 8 == 0)
    const int bm = (swz & 31) * 128;
    const int bn = (swz >> 5) * 128;

    const int tid = threadIdx.x;
    const int w = tid >> 6, l = tid & 63, g = l >> 4, lc = l & 15;
    const int wr = (w >> 1) * 64, wc = (w & 1) * 64;
    const int row = tid >> 2, ch = tid & 3;

    const __bf16* Ap = A  + (size_t)(bm + row) * K + ch * 8;
    const __bf16* Bp = Bw + (size_t)(bn + row) * K + ch * 8;
    __bf16* AsLo = &As[w * 512];
    __bf16* AsHi = &As[2048 + w * 512];
    __bf16* BsLo = &Bs[w * 512];
    __bf16* BsHi = &Bs[2048 + w * 512];

    f32x4 acc[4][4];
    const f32x4 z4 = {0.f, 0.f, 0.f, 0.f};
#pragma unroll
    for (int i = 0; i < 4; ++i)
#pragma unroll
        for (int j = 0; j < 4; ++j) acc[i][j] = z4;

    for (int kt = 0; kt < K; kt += 32) {
        gload16(Ap + kt,                   AsLo);
        gload16(Ap + kt + (size_t)64 * K,  AsHi);
        gload16(Bp + kt,                   BsLo);
        gload16(Bp + kt + (size_t)64 * K,  BsHi);
        __syncthreads();

        bf16x8 af[4], bfr[4];
#pragma unroll
        for (int i = 0; i < 4; ++i)
            af[i] = *(const bf16x8*)&As[(wr + i * 16 + lc) * 32 + g * 8];
#pragma unroll
        for (int j = 0; j < 4; ++j)
            bfr[j] = *(const bf16x8*)&Bs[(wc + j * 16 + lc) * 32 + g * 8];
        __builtin_amdgcn_s_setprio(1);
#pragma unroll
        for (int i = 0; i < 4; ++i)
#pragma unroll
            for (int j = 0; j < 4; ++j)
                acc[i][j] = __builtin_amdgcn_mfma_f32_16x16x32_bf16(af[i], bfr[j], acc[i][j], 0, 0, 0);
        __builtin_amdgcn_s_setprio(0);
        __syncthreads();
    }

#pragma unroll
    for (int i = 0; i < 4; ++i) {
        int r0 = bm + wr + i * 16 + g * 4;
#pragma unroll
        for (int j = 0; j < 4; ++j) {
            int c = bn + wc + j * 16 + lc;
            float bb = bias[c];
#pragma unroll
            for (int r = 0; r < 4; ++r)
                C[(size_t)(r0 + r) * N + c] = (__bf16)(acc[i][j][r] + bb);
        }
    }
}

// ---------------------------------------------------------------- out GEMM (reg-prefetch structure)
__global__ __launch_bounds__(256) void gemm_out(const __bf16* __restrict__ A,
                                                const __bf16* __restrict__ Bw,
                                                const float* __restrict__ bias,
                                                float* __restrict__ Cout) {
    __shared__ __bf16 As[128 * 32];
    __shared__ __bf16 Bs[128 * 32];
    const int M = MTOT, N = HIDDEN, K = HIDDEN;

    const int tid = threadIdx.x;
    const int w = tid >> 6, l = tid & 63, g = l >> 4, lc = l & 15;
    const int wr = (w >> 1) * 64, wc = (w & 1) * 64;
    const int bm = blockIdx.x * 128, bn = blockIdx.y * 128;
    const int row = tid >> 2, ch = tid & 3;

    const __bf16* Arow0 = A  + (size_t)(bm + row) * K + ch * 8;
    const __bf16* Arow1 = Arow0 + (size_t)64 * K;
    const __bf16* Brow0 = Bw + (size_t)(bn + row) * K + ch * 8;
    const __bf16* Brow1 = Brow0 + (size_t)64 * K;

    f32x4 acc[4][4];
    const f32x4 z4 = {0.f, 0.f, 0.f, 0.f};
#pragma unroll
    for (int i = 0; i < 4; ++i)
#pragma unroll
        for (int j = 0; j < 4; ++j) acc[i][j] = z4;

    int4 ra0 = *(const int4*)(Arow0);
    int4 ra1 = *(const int4*)(Arow1);
    int4 rb0 = *(const int4*)(Brow0);
    int4 rb1 = *(const int4*)(Brow1);

    for (int kt = 0; kt < K; kt += 32) {
        *(int4*)&As[row * 32 + ch * 8]        = ra0;
        *(int4*)&As[(64 + row) * 32 + ch * 8] = ra1;
        *(int4*)&Bs[row * 32 + ch * 8]        = rb0;
        *(int4*)&Bs[(64 + row) * 32 + ch * 8] = rb1;
        __syncthreads();

        if (kt + 32 < K) {
            ra0 = *(const int4*)(Arow0 + kt + 32);
            ra1 = *(const int4*)(Arow1 + kt + 32);
            rb0 = *(const int4*)(Brow0 + kt + 32);
            rb1 = *(const int4*)(Brow1 + kt + 32);
        }

        bf16x8 af[4], bfr[4];
#pragma unroll
        for (int i = 0; i < 4; ++i)
            af[i] = *(const bf16x8*)&As[(wr + i * 16 + lc) * 32 + g * 8];
#pragma unroll
        for (int j = 0; j < 4; ++j)
            bfr[j] = *(const bf16x8*)&Bs[(wc + j * 16 + lc) * 32 + g * 8];
        __builtin_amdgcn_s_setprio(1);
#pragma unroll
        for (int i = 0; i < 4; ++i)
#pragma unroll
            for (int j = 0; j < 4; ++j)
                acc[i][j] = __builtin_amdgcn_mfma_f32_16x16x32_bf16(af[i], bfr[j], acc[i][j], 0, 0, 0);
        __builtin_amdgcn_s_setprio(0);
        __syncthreads();
    }

#pragma unroll
    for (int i = 0; i < 4; ++i) {
        int r0 = bm + wr + i * 16 + g * 4;
#pragma unroll
        for (int j = 0; j < 4; ++j) {
            int c = bn + wc + j * 16 + lc;
            float bb = bias[c];
#pragma unroll
            for (int r = 0; r < 4; ++r)
                Cout[(size_t)(r0 + r) * N + c] = acc[i][j][r] + bb;
        }
    }
}

// ---------------------------------------------------------------- flash attention
// QKV [4096][3072] bf16 (Q cols pre-scaled to log2 domain); Vt [B*H][DH][SEQL]; Ctx [MTOT][HIDDEN].
// grid = 512 (XCD-swizzled), block = 256 (4 waves, 32 q-rows each).
__global__ __launch_bounds__(256) void attn_kernel(const __bf16* __restrict__ QKV,
                                                   const __bf16* __restrict__ Vt,
                                                   __bf16* __restrict__ Ctx) {
    __shared__ __bf16 k_lds[2][64][64];   // XOR-swizzled via pre-swizzled global src
    __shared__ __bf16 v_lds[2][64][64];
    __shared__ float  bc[4][32];

    const int tid = threadIdx.x;
    const int w  = tid >> 6;
    const int l  = tid & 63;
    const int ql = l & 31;
    const int lh = l >> 5;

    int bid = blockIdx.x;                       // 512 blocks
    int swz = (bid & 7) * 64 + (bid >> 3);      // XCD-chunked
    const int qt = swz & 15, bh = swz >> 4;
    const int b = bh >> 4, hd = bh & 15;
    const int qw = qt * 128 + w * 32;

    const __bf16* Qg = QKV + (size_t)b * SEQL * QKVLD + hd * DH;
    const __bf16* Kg = Qg + 1024;
    const __bf16* Vg = Vt + (size_t)bh * DH * SEQL;

    // Q fragments (B-operand)
    bf16x8 qf[4];
    {
        const __bf16* qp = Qg + (size_t)(qw + ql) * QKVLD + lh * 8;
#pragma unroll
        for (int c = 0; c < 4; ++c) qf[c] = *(const bf16x8*)(qp + c * 16);
    }

    // staging via global_load_lds: linear LDS dest, inverse-swizzled global source
    const int sr   = l >> 3;                     // 0..7
    const int gcol = ((l & 7) * 8) ^ (sr << 3);  // pre-swizzled source column
    auto stage = [&](int kb, int nb) {
        const __bf16* kp = Kg + (size_t)(kb + w * 8 + sr) * QKVLD + gcol;
        const __bf16* vp = Vg + (size_t)(w * 8 + sr) * SEQL + kb + gcol;
        gload16(kp,                          &k_lds[nb][w * 8][0]);
        gload16(kp + (size_t)32 * QKVLD,     &k_lds[nb][32 + w * 8][0]);
        gload16(vp,                          &v_lds[nb][w * 8][0]);
        gload16(vp + (size_t)32 * SEQL,      &v_lds[nb][32 + w * 8][0]);
    };

    stage(0, 0);
    __syncthreads();

    f32x16 o0, o1;
#pragma unroll
    for (int r = 0; r < 16; ++r) { o0[r] = 0.f; o1[r] = 0.f; }
    float m_r = -1e30f, l_r = 0.f;

    const int NT = SEQL / 64;
    const int rsw = (ql & 7) << 3;

    for (int kt = 0; kt < NT; ++kt) {
        const int buf = kt & 1;
        const int kb = kt * 64;

        if (kt + 1 < NT) stage(kb + 64, buf ^ 1);   // loads fly across this iteration

        // ---- QK^T (swapped: A=K, B=Q)
        f32x16 sA, sB;
#pragma unroll
        for (int r = 0; r < 16; ++r) { sA[r] = 0.f; sB[r] = 0.f; }
        __builtin_amdgcn_s_setprio(1);
#pragma unroll
        for (int c = 0; c < 4; ++c) {
            bf16x8 k0 = *(const bf16x8*)&k_lds[buf][ql]     [(c * 16 + lh * 8) ^ rsw];
            bf16x8 k1 = *(const bf16x8*)&k_lds[buf][32 + ql][(c * 16 + lh * 8) ^ rsw];
            sA = __builtin_amdgcn_mfma_f32_32x32x16_bf16(k0, qf[c], sA, 0, 0, 0);
            sB = __builtin_amdgcn_mfma_f32_32x32x16_bf16(k1, qf[c], sB, 0, 0, 0);
        }
        __builtin_amdgcn_s_setprio(0);

        float p[32];
#pragma unroll
        for (int r = 0; r < 16; ++r) { p[r] = sA[r]; p[16 + r] = sB[r]; }

        // diagonal mask (wave-uniform branch)
        if (kb < qw + 32 && qw < kb + 64) {
            const int qg = qw + ql;
#pragma unroll
            for (int i = 0; i < 32; ++i) {
                int kg = kb + ((i >> 4) << 5) + (i & 3) + ((i >> 2) & 3) * 8 + lh * 4;
                if (kg == qg) p[i] = -1e30f;
            }
        }

        // row max: pairwise tree (depth 5) + cross-half
        float t16[16];
#pragma unroll
        for (int i = 0; i < 16; ++i) t16[i] = fmaxf(p[i], p[i + 16]);
#pragma unroll
        for (int i = 0; i < 8; ++i) t16[i] = fmaxf(t16[i], t16[i + 8]);
#pragma unroll
        for (int i = 0; i < 4; ++i) t16[i] = fmaxf(t16[i], t16[i + 4]);
        float pm = fmaxf(fmaxf(t16[0], t16[1]), fmaxf(t16[2], t16[3]));
        pm = fmaxf(pm, __shfl_xor(pm, 32, 64));

        // defer-max rescale (log2 domain, THR=8 -> P bounded by 256)
        if (__any(pm > m_r + 8.f)) {
            float mn = fmaxf(m_r, pm);
            float al = exp2fast(m_r - mn);
            m_r = mn;
            l_r *= al;
            if (lh == 0) bc[w][ql] = al;
            asm volatile("s_waitcnt lgkmcnt(0)" ::: "memory");
            float ag[16];
#pragma unroll
            for (int r = 0; r < 16; ++r)
                ag[r] = bc[w][(r & 3) + (r >> 2) * 8 + lh * 4];
#pragma unroll
            for (int r = 0; r < 16; ++r) { o0[r] *= ag[r]; o1[r] *= ag[r]; }
        }

        // exp2 + tree row-sum
#pragma unroll
        for (int i = 0; i < 32; ++i) p[i] = exp2fast(p[i] - m_r);
        float s16[16];
#pragma unroll
        for (int i = 0; i < 16; ++i) s16[i] = p[i] + p[i + 16];
#pragma unroll
        for (int i = 0; i < 8; ++i) s16[i] += s16[i + 8];
#pragma unroll
        for (int i = 0; i < 4; ++i) s16[i] += s16[i + 4];
        float rs = (s16[0] + s16[1]) + (s16[2] + s16[3]);
        rs += __shfl_xor(rs, 32, 64);
        l_r += rs;

        // P -> bf16 PV A-fragments in-register (T12)
        bf16x8 pa[4];
#pragma unroll
        for (int s = 0; s < 2; ++s) {
            unsigned w0 = cvtpk(p[s * 16 + 0],  p[s * 16 + 1]);
            unsigned w1 = cvtpk(p[s * 16 + 2],  p[s * 16 + 3]);
            unsigned w2 = cvtpk(p[s * 16 + 4],  p[s * 16 + 5]);
            unsigned w3 = cvtpk(p[s * 16 + 6],  p[s * 16 + 7]);
            unsigned w4 = cvtpk(p[s * 16 + 8],  p[s * 16 + 9]);
            unsigned w5 = cvtpk(p[s * 16 + 10], p[s * 16 + 11]);
            unsigned w6 = cvtpk(p[s * 16 + 12], p[s * 16 + 13]);
            unsigned w7 = cvtpk(p[s * 16 + 14], p[s * 16 + 15]);
            pswap(w0, w2); pswap(w1, w3);
            pswap(w4, w6); pswap(w5, w7);
            uint4 lo4 = {w0, w1, w2, w3};
            uint4 hi4 = {w4, w5, w6, w7};
            pa[s * 2 + 0] = *(bf16x8*)&lo4;
            pa[s * 2 + 1] = *(bf16x8*)&hi4;
        }

        // ---- PV
        __builtin_amdgcn_s_setprio(1);
#pragma unroll
        for (int s = 0; s < 2; ++s)
#pragma unroll
            for (int sl = 0; sl < 2; ++sl) {
                const int col = s * 32 + sl * 16 + lh * 8;
                bf16x8 v0 = *(const bf16x8*)&v_lds[buf][ql]     [col ^ rsw];
                bf16x8 v1 = *(const bf16x8*)&v_lds[buf][32 + ql][col ^ rsw];
                o0 = __builtin_amdgcn_mfma_f32_32x32x16_bf16(pa[s * 2 + sl], v0, o0, 0, 0, 0);
                o1 = __builtin_amdgcn_mfma_f32_32x32x16_bf16(pa[s * 2 + sl], v1, o1, 0, 0, 0);
            }
        __builtin_amdgcn_s_setprio(0);

        __syncthreads();   // drains vmcnt -> buf^1 staged; all waves done reading buf
    }

    if (lh == 0) bc[w][ql] = 1.f / l_r;
    asm volatile("s_waitcnt lgkmcnt(0)" ::: "memory");
#pragma unroll
    for (int r = 0; r < 16; ++r) {
        int cr = (r & 3) + (r >> 2) * 8 + lh * 4;
        float iv = bc[w][cr];
        int qrow = qw + cr;
        __bf16* cp = Ctx + (size_t)(b * SEQL + qrow) * HIDDEN + hd * DH + ql;
        cp[0]  = (__bf16)(o0[r] * iv);
        cp[32] = (__bf16)(o1[r] * iv);
    }
}

// ---------------------------------------------------------------- launch
extern "C" void kernel_launch(void* const* d_in, const int* in_sizes, int n_in,
                              void* d_out, int out_size, void* d_ws, size_t ws_size,
                              hipStream_t stream) {
    const float* H  = (const float*)d_in[0];
    const float* Wq = (const float*)d_in[1];
    const float* bq = (const float*)d_in[2];
    const float* Wk = (const float*)d_in[3];
    const float* bk = (const float*)d_in[4];
    const float* Wv = (const float*)d_in[5];
    const float* bv = (const float*)d_in[6];
    const float* Wd = (const float*)d_in[7];
    const float* bd = (const float*)d_in[8];
    float* out = (float*)d_out;

    char* ws = (char*)d_ws;
    const size_t MB = 1024 * 1024;
    __bf16* Hb    = (__bf16*)(ws + 0 * MB);    // 8 MB (dead after QKV gemm)
    __bf16* Ctx   = (__bf16*)(ws + 0 * MB);    // aliases Hb (written by attn, after Hb is dead)
    __bf16* Wqkvb = (__bf16*)(ws + 8 * MB);    // 6 MB [Wq*s | Wk | Wv]
    __bf16* Wdb   = (__bf16*)(ws + 14 * MB);   // 2 MB (contiguous after Wv for cvt_w4)
    float*  bqkv  = (float*) (ws + 16 * MB);   // 12 KB
    __bf16* QKV   = (__bf16*)(ws + 17 * MB);   // 24 MB
    __bf16* Vtb   = (__bf16*)(ws + 41 * MB);   // 8 MB -> 49 MB total
    if (ws_size < 49 * MB) return;

    cvt_f32_bf16<<<4096, 256, 0, stream>>>(H, Hb, MTOT * HIDDEN / 4);
    cvt_w4<<<dim3(1024, 4), 256, 0, stream>>>(Wq, Wk, Wv, Wd, Wqkvb);
    pack_bias<<<12, 256, 0, stream>>>(bq, bk, bv, bqkv);

    gemm_qkv<<<768, 256, 0, stream>>>(Hb, Wqkvb, bqkv, QKV);

    transpose_v<<<dim3(32, 32), 256, 0, stream>>>(QKV, Vtb);

    attn_kernel<<<512, 256, 0, stream>>>(QKV, Vtb, Ctx);

    gemm_out<<<dim3(32, 8), 256, 0, stream>>>(Ctx, Wdb, bd, out);
}